// Round 11
// baseline (179.593 us; speedup 1.0000x reference)
//
#include <hip/hip_runtime.h>

// GCN encoder: 2x (dense transform -> symmetric-normalized neighbor aggregation)
// R3: bf16x3 split MFMA GEMMs (no fp32 MFMA on CDNA4), W pre-swizzled.
// R4: aggregation gather tables bf16 -> halved beyond-L2 gather traffic.
// R5 FAILED: cross-thread fence race in ticket scan -> OOB -> abort.
// R6/R7: race-free fusions + atomic-free bucketed CSR build.
// R8 FAILED / R9 REGRESSED: cooperative grid.sync costs ~100 us on MI355X
//     (device-wide flush across 8 non-coherent XCD L2s); multi-dispatch wins.
// R10: 6 dispatches, 173.8 us. Marginal boundary cost measured ~2-4 us.
// R11: fuse agg1+gemm2 (5 dispatches = dependency minimum). Block owns 64
//     nodes; each wave aggregates 16 nodes -> bf16 hi/lo into a padded LDS
//     tile (stride 136 ushorts -> only 2-way bank aliasing, free), then runs
//     its own 16 gemm2 rows from LDS (wave reads only rows it wrote -> no
//     __syncthreads). h1 (51 MB round-trip) never touches global.

typedef __attribute__((ext_vector_type(8))) short short8;
typedef __attribute__((ext_vector_type(4))) float float4v;

constexpr int PB = 128;   // partition blocks (histogram/scatter chunks)
constexpr int LDA = 136;  // LDS row stride in ushorts (128 + 8 pad)

static __device__ __forceinline__ ushort f2bf(float f) {
  union { float f; unsigned u; } c; c.f = f;
  unsigned u = c.u;
  return (ushort)((u + 0x7fffu + ((u >> 16) & 1u)) >> 16);  // RNE
}
static __device__ __forceinline__ float bf2f(ushort h) {
  union { unsigned u; float f; } c; c.u = ((unsigned)h) << 16;
  return c.f;
}
static __device__ __forceinline__ float bfhi(unsigned packed) {
  union { unsigned u; float f; } c; c.u = packed & 0xffff0000u;
  return c.f;
}
static __device__ __forceinline__ float bflo(unsigned packed) {
  union { unsigned u; float f; } c; c.u = packed << 16;
  return c.f;
}

struct MegaParams {
  const float* x;
  const int* src;
  const int* dst;
  const float* W1;
  const float* b1;
  const float* W2;
  const float* b2;
  int N, E, NBK, EPB, GB, NAGG;
  int* cnt_mat;
  int* bases;      // [NBK+1] bucket base offsets (published by scatter kernel)
  unsigned* part;
  int* row_ptr;
  float* dinv;
  int* col;
  ushort* h;
  ushort* h2;
  ushort* w1hi;
  ushort* w1lo;
  ushort* w2hi;
  ushort* w2lo;
  float* out;
};

// W swizzle: one 16x32 B-fragment tile (64 lanes).
// Layout [ktile][ntile][lane][j]: B[k=(lane>>4)*8+j][n=lane&15]
static __device__ __forceinline__ void wswz_tile(const float* __restrict__ W,
                                                 ushort* __restrict__ whi,
                                                 ushort* __restrict__ wlo,
                                                 int M, int tile, int lane) {
  int ntiles = M >> 4;
  int kt = tile / ntiles, nt = tile % ntiles;
  int colg = nt * 16 + (lane & 15);
  int krow = kt * 32 + (lane >> 4) * 8;
  size_t o = ((size_t)tile * 64 + lane) * 8;
#pragma unroll
  for (int j = 0; j < 8; j++) {
    float v = W[(size_t)(krow + j) * M + colg];
    ushort h = f2bf(v);
    whi[o + j] = h;
    wlo[o + j] = f2bf(v - bf2f(h));
  }
}

// ---- K1: bucket histogram (bid<PB) + W swizzles (bid in [PB,PB+12)) ------
__global__ __launch_bounds__(256) void k_g1(MegaParams P) {
  __shared__ int hist[512];
  int bid = blockIdx.x, t = threadIdx.x;
  if (bid >= PB) {
    int tile = (bid - PB) * 4 + (t >> 6);
    int lane = t & 63;
    if (tile < 32) wswz_tile(P.W1, P.w1hi, P.w1lo, 128, tile, lane);
    else           wswz_tile(P.W2, P.w2hi, P.w2lo, 64, tile - 32, lane);
    return;
  }
  for (int k = t; k < P.NBK; k += 256) hist[k] = 0;
  __syncthreads();
  int start = bid * P.EPB;
  int stop = min(P.E, start + P.EPB);
  for (int e = start + t * 4; e < stop; e += 1024) {
    if (e + 4 <= stop) {
      int4 d = *(const int4*)(P.dst + e);
      atomicAdd(&hist[d.x >> 7], 1);
      atomicAdd(&hist[d.y >> 7], 1);
      atomicAdd(&hist[d.z >> 7], 1);
      atomicAdd(&hist[d.w >> 7], 1);
    } else {
      for (int j = e; j < stop; j++) atomicAdd(&hist[P.dst[j] >> 7], 1);
    }
  }
  __syncthreads();
  for (int k = t; k < P.NBK; k += 256) P.cnt_mat[k * PB + bid] = hist[k];
}

// ---- gemm1 block: C[64 rows, 128] = A @ W1, fp32 A split to bf16 hi/lo ----
static __device__ void gemm1_block(int gb, const MegaParams& P) {
  constexpr int K = 128, M = 128, NT = M / 16;
  int t = threadIdx.x;
  int lane = t & 63;
  int wv = t >> 6;
  int quad = lane >> 4, lo16 = lane & 15;
  int rowbase = gb * 64 + wv * 16;
  int arow = rowbase + lo16;
  bool arow_ok = arow < P.N;
  float4v acc[NT];
#pragma unroll
  for (int nt = 0; nt < NT; nt++) acc[nt] = (float4v){0.f, 0.f, 0.f, 0.f};
  for (int kt = 0; kt < 4; kt++) {
    short8 ahi, alo;
    float av[8];
    if (arow_ok) {
      const float* ap = P.x + (size_t)arow * K + kt * 32 + quad * 8;
      float4 a0 = *(const float4*)ap;
      float4 a1 = *(const float4*)(ap + 4);
      av[0] = a0.x; av[1] = a0.y; av[2] = a0.z; av[3] = a0.w;
      av[4] = a1.x; av[5] = a1.y; av[6] = a1.z; av[7] = a1.w;
    } else {
#pragma unroll
      for (int j = 0; j < 8; j++) av[j] = 0.f;
    }
#pragma unroll
    for (int j = 0; j < 8; j++) {
      ushort hh = f2bf(av[j]);
      ahi[j] = (short)hh;
      alo[j] = (short)f2bf(av[j] - bf2f(hh));
    }
    const ushort* ph = P.w1hi + ((size_t)(kt * NT) * 64 + lane) * 8;
    const ushort* pl = P.w1lo + ((size_t)(kt * NT) * 64 + lane) * 8;
#pragma unroll
    for (int nt = 0; nt < NT; nt++) {
      short8 bhi = *(const short8*)(ph + nt * 512);
      short8 blo = *(const short8*)(pl + nt * 512);
      acc[nt] = __builtin_amdgcn_mfma_f32_16x16x32_bf16(ahi, bhi, acc[nt], 0, 0, 0);
      acc[nt] = __builtin_amdgcn_mfma_f32_16x16x32_bf16(alo, bhi, acc[nt], 0, 0, 0);
      acc[nt] = __builtin_amdgcn_mfma_f32_16x16x32_bf16(ahi, blo, acc[nt], 0, 0, 0);
    }
  }
  // D layout (m89-verified): col = lane&15, row = quad*4 + reg
#pragma unroll
  for (int nt = 0; nt < NT; nt++) {
#pragma unroll
    for (int r = 0; r < 4; r++) {
      int row = rowbase + quad * 4 + r;
      if (row < P.N) P.h[(size_t)row * M + nt * 16 + lo16] = f2bf(acc[nt][r]);
    }
  }
}

// ---- K2: partition scatter w/ self-computed prefixes (bid<PB) || gemm1 ----
__global__ __launch_bounds__(256) void k_g2(MegaParams P) {
  __shared__ int buf[256];
  __shared__ int base[512];
  __shared__ int tot[512];
  __shared__ int cur[512];
  int bid = blockIdx.x, t = threadIdx.x;
  if (bid >= PB) {
    gemm1_block(bid - PB, P);
    return;
  }
  for (int k = t; k < P.NBK; k += 256) {
    const int* row = P.cnt_mat + (size_t)k * PB;
    int pre = 0, s = 0;
    for (int b = 0; b < PB; b++) {
      int c = row[b];
      s += c;
      if (b < bid) pre += c;
    }
    tot[k] = s;
    cur[k] = pre;
  }
  __syncthreads();
  {
    int carry = 0;
    for (int b0 = 0; b0 < 512; b0 += 256) {
      int idx = b0 + t;
      int v = (idx < P.NBK) ? tot[idx] : 0;
      buf[t] = v;
      __syncthreads();
      for (int off = 1; off < 256; off <<= 1) {
        int add = (t >= off) ? buf[t - off] : 0;
        __syncthreads();
        buf[t] += add;
        __syncthreads();
      }
      base[idx] = carry + buf[t] - v;
      carry += buf[255];
      __syncthreads();
    }
  }
  for (int k = t; k < P.NBK; k += 256) cur[k] += base[k];
  if (bid == 0)
    for (int k = t; k <= P.NBK; k += 256) P.bases[k] = base[k];
  __syncthreads();
  int start = bid * P.EPB, stop = min(P.E, start + P.EPB);
  for (int e = start + t * 4; e < stop; e += 1024) {
    if (e + 4 <= stop) {
      int4 s = *(const int4*)(P.src + e);
      int4 d = *(const int4*)(P.dst + e);
      int p;
      p = atomicAdd(&cur[d.x >> 7], 1); P.part[p] = (unsigned)s.x | ((unsigned)(d.x & 127) << 25);
      p = atomicAdd(&cur[d.y >> 7], 1); P.part[p] = (unsigned)s.y | ((unsigned)(d.y & 127) << 25);
      p = atomicAdd(&cur[d.z >> 7], 1); P.part[p] = (unsigned)s.z | ((unsigned)(d.z & 127) << 25);
      p = atomicAdd(&cur[d.w >> 7], 1); P.part[p] = (unsigned)s.w | ((unsigned)(d.w & 127) << 25);
    } else {
      for (int j = e; j < stop; j++) {
        int p2 = atomicAdd(&cur[P.dst[j] >> 7], 1);
        P.part[p2] = (unsigned)P.src[j] | ((unsigned)(P.dst[j] & 127) << 25);
      }
    }
  }
}

// ---- K3: per-bucket local CSR (LDS count/scan/place); bases from K2 -------
__global__ __launch_bounds__(256) void k_g3(MegaParams P) {
  __shared__ int buf[256];
  __shared__ int cnt[128];
  __shared__ int cur[128];
  int bid = blockIdx.x, t = threadIdx.x;
  int beg = P.bases[bid], end = P.bases[bid + 1];
  if (t < 128) cnt[t] = 0;
  __syncthreads();
  for (int e = beg + t; e < end; e += 256) atomicAdd(&cnt[P.part[e] >> 25], 1);
  __syncthreads();
  int v = (t < 128) ? cnt[t] : 0;
  buf[t] = v;
  __syncthreads();
#pragma unroll
  for (int off = 1; off < 256; off <<= 1) {
    int add = (t >= off) ? buf[t - off] : 0;
    __syncthreads();
    buf[t] += add;
    __syncthreads();
  }
  if (t < 128) {
    int excl = buf[t] - v;
    cur[t] = beg + excl;
    int node = bid * 128 + t;
    if (node < P.N) {
      P.row_ptr[node] = beg + excl;
      P.dinv[node] = rsqrtf((float)(v + 1));  // +1 self loop
    }
  }
  if (bid == 0 && t == 0) P.row_ptr[P.N] = P.E;
  __syncthreads();
  for (int e = beg + t; e < end; e += 256) {
    unsigned p = P.part[e];
    int pos = atomicAdd(&cur[p >> 25], 1);
    P.col[pos] = (int)(p & 0x01FFFFFFu);
  }
}

// ---- aggregation core for one node (C channels across lanes) -------------
template <int C>
static __device__ __forceinline__ void agg_node(int v, const MegaParams& P,
                                                const ushort* __restrict__ Hb,
                                                int lane, float dv,
                                                float& acc0, float& acc1) {
  constexpr int VPL = C / 64;
  auto loadp = [&](int s) -> unsigned {
    if (VPL == 2) return *(const unsigned*)(Hb + (size_t)s * C + lane * 2);
    else          return (unsigned)Hb[(size_t)s * C + lane];
  };
  {
    unsigned u = loadp(v);  // self loop (weight dv)
    if (VPL == 2) { acc0 = dv * bflo(u); acc1 = dv * bfhi(u); }
    else          { acc0 = dv * bf2f((ushort)u); acc1 = 0.f; }
  }
  int beg = P.row_ptr[v], end = P.row_ptr[v + 1];
  for (int base = beg; base < end; base += 64) {
    int m = end - base;
    if (m > 64) m = 64;
    int sl = 0;
    float wl = 0.f;
    if (lane < m) {
      sl = P.col[base + lane];
      wl = P.dinv[sl];
    }
    int j = 0;
    for (; j + 8 <= m; j += 8) {
      int s[8]; float wq[8]; unsigned u[8];
#pragma unroll
      for (int q = 0; q < 8; q++) { s[q] = __shfl(sl, j + q); wq[q] = __shfl(wl, j + q); }
#pragma unroll
      for (int q = 0; q < 8; q++) u[q] = loadp(s[q]);
#pragma unroll
      for (int q = 0; q < 8; q++) {
        if (VPL == 2) {
          acc0 = fmaf(wq[q], bflo(u[q]), acc0);
          acc1 = fmaf(wq[q], bfhi(u[q]), acc1);
        } else {
          acc0 = fmaf(wq[q], bf2f((ushort)u[q]), acc0);
        }
      }
    }
    for (; j + 4 <= m; j += 4) {
      int s[4]; float wq[4]; unsigned u[4];
#pragma unroll
      for (int q = 0; q < 4; q++) { s[q] = __shfl(sl, j + q); wq[q] = __shfl(wl, j + q); }
#pragma unroll
      for (int q = 0; q < 4; q++) u[q] = loadp(s[q]);
#pragma unroll
      for (int q = 0; q < 4; q++) {
        if (VPL == 2) {
          acc0 = fmaf(wq[q], bflo(u[q]), acc0);
          acc1 = fmaf(wq[q], bfhi(u[q]), acc1);
        } else {
          acc0 = fmaf(wq[q], bf2f((ushort)u[q]), acc0);
        }
      }
    }
    for (; j < m; j++) {
      int s = __shfl(sl, j);
      float wv = __shfl(wl, j);
      unsigned u = loadp(s);
      if (VPL == 2) {
        acc0 = fmaf(wv, bflo(u), acc0);
        acc1 = fmaf(wv, bfhi(u), acc1);
      } else {
        acc0 = fmaf(wv, bf2f((ushort)u), acc0);
      }
    }
  }
}

// ---- K4: fused agg1 + gemm2. Block owns 64 nodes; wave wv aggregates nodes
// [wv*16, wv*16+16) into the LDS hi/lo tile, then runs gemm2 on exactly
// those 16 rows (its own writes -> no __syncthreads needed). ---------------
__global__ __launch_bounds__(256) void k_g45(MegaParams P) {
  __shared__ ushort Ahi[64 * LDA];  // 17.4 KB (+pad breaks 16-way conflicts)
  __shared__ ushort Alo[64 * LDA];  // 17.4 KB
  int t = threadIdx.x;
  int lane = t & 63, wv = t >> 6;
  int nodebase = blockIdx.x * 64 + wv * 16;

  // phase A: aggregate 16 nodes (C=128: 2 channels/lane), ReLU, split hi/lo
  for (int i = 0; i < 16; i++) {
    int v = nodebase + i;
    int lrow = wv * 16 + i;
    unsigned uh = 0, ul = 0;
    if (v < P.N) {
      float dv = P.dinv[v];
      float a0, a1;
      agg_node<128>(v, P, P.h, lane, dv, a0, a1);
      float r0 = fmaxf(fmaf(dv, a0, P.b1[lane * 2 + 0]), 0.f);
      float r1 = fmaxf(fmaf(dv, a1, P.b1[lane * 2 + 1]), 0.f);
      ushort h0 = f2bf(r0), h1 = f2bf(r1);
      ushort l0 = f2bf(r0 - bf2f(h0)), l1 = f2bf(r1 - bf2f(h1));
      uh = (unsigned)h0 | ((unsigned)h1 << 16);
      ul = (unsigned)l0 | ((unsigned)l1 << 16);
    }
    *(unsigned*)&Ahi[lrow * LDA + lane * 2] = uh;
    *(unsigned*)&Alo[lrow * LDA + lane * 2] = ul;
  }

  // phase B: gemm2 rows [nodebase, nodebase+16) from LDS A + global W2 frags
  constexpr int K = 128, M = 64, NT = M / 16;
  int quad = lane >> 4, lo16 = lane & 15;
  float4v acc[NT];
#pragma unroll
  for (int nt = 0; nt < NT; nt++) acc[nt] = (float4v){0.f, 0.f, 0.f, 0.f};
  for (int kt = 0; kt < 4; kt++) {
    int lrow = wv * 16 + lo16;
    int ko = kt * 32 + quad * 8;
    short8 ahi = *(const short8*)&Ahi[lrow * LDA + ko];  // 16B ds_read, aligned (LDA*2=272=17*16)
    short8 alo = *(const short8*)&Alo[lrow * LDA + ko];
    const ushort* ph = P.w2hi + ((size_t)(kt * NT) * 64 + lane) * 8;
    const ushort* pl = P.w2lo + ((size_t)(kt * NT) * 64 + lane) * 8;
#pragma unroll
    for (int nt = 0; nt < NT; nt++) {
      short8 bhi = *(const short8*)(ph + nt * 512);
      short8 blo = *(const short8*)(pl + nt * 512);
      acc[nt] = __builtin_amdgcn_mfma_f32_16x16x32_bf16(ahi, bhi, acc[nt], 0, 0, 0);
      acc[nt] = __builtin_amdgcn_mfma_f32_16x16x32_bf16(alo, bhi, acc[nt], 0, 0, 0);
      acc[nt] = __builtin_amdgcn_mfma_f32_16x16x32_bf16(ahi, blo, acc[nt], 0, 0, 0);
    }
  }
#pragma unroll
  for (int nt = 0; nt < NT; nt++) {
#pragma unroll
    for (int r = 0; r < 4; r++) {
      int row = nodebase + quad * 4 + r;
      if (row < P.N) P.h2[(size_t)row * M + nt * 16 + lo16] = f2bf(acc[nt][r]);
    }
  }
}

// ---- K5: aggregation layer 2 (C=64, final fp32 out) ----------------------
__global__ __launch_bounds__(256) void k_g6(MegaParams P) {
  int lane = threadIdx.x & 63;
  int v = blockIdx.x * 4 + (threadIdx.x >> 6);
  if (v >= P.N) return;
  float dv = P.dinv[v];
  float a0, a1;
  agg_node<64>(v, P, P.h2, lane, dv, a0, a1);
  P.out[(size_t)v * 64 + lane] = fmaf(dv, a0, P.b2[lane]);
}

extern "C" void kernel_launch(void* const* d_in, const int* in_sizes, int n_in,
                              void* d_out, int out_size, void* d_ws, size_t ws_size,
                              hipStream_t stream) {
  MegaParams P;
  P.x  = (const float*)d_in[0];
  const int* ei = (const int*)d_in[1];
  P.W1 = (const float*)d_in[2];
  P.b1 = (const float*)d_in[3];
  P.W2 = (const float*)d_in[4];
  P.b2 = (const float*)d_in[5];
  P.N = in_sizes[0] / 128;
  P.E = in_sizes[1] / 2;
  P.src = ei;
  P.dst = ei + P.E;
  P.NBK = (P.N + 127) / 128;                   // 391; must be <= 511
  P.EPB = ((P.E + PB - 1) / PB + 3) & ~3;      // edges per partition block, x4
  P.GB = (P.N + 63) / 64;                      // 782
  P.NAGG = (P.N + 3) / 4;                      // 12500

  auto al = [](size_t v) { return (v + 255) & ~(size_t)255; };
  char* w = (char*)d_ws;
  P.cnt_mat = (int*)w;      w += al((size_t)P.NBK * PB * 4);
  P.bases   = (int*)w;      w += al((size_t)(P.NBK + 1) * 4);
  P.part    = (unsigned*)w; w += al((size_t)P.E * 4);
  P.row_ptr = (int*)w;      w += al((size_t)(P.N + 1) * 4);
  P.dinv    = (float*)w;    w += al((size_t)P.N * 4);
  P.col     = (int*)w;      w += al((size_t)P.E * 4);
  P.h       = (ushort*)w;   w += al((size_t)P.N * 128 * 2);
  P.h2      = (ushort*)w;   w += al((size_t)P.N * 64 * 2);
  P.w1hi    = (ushort*)w;   w += al((size_t)128 * 128 * 2);
  P.w1lo    = (ushort*)w;   w += al((size_t)128 * 128 * 2);
  P.w2hi    = (ushort*)w;   w += al((size_t)128 * 64 * 2);
  P.w2lo    = (ushort*)w;   w += al((size_t)128 * 64 * 2);
  P.out = (float*)d_out;

  k_g1<<<PB + 12, 256, 0, stream>>>(P);
  k_g2<<<PB + P.GB, 256, 0, stream>>>(P);
  k_g3<<<P.NBK, 256, 0, stream>>>(P);
  k_g45<<<P.GB, 256, 0, stream>>>(P);
  k_g6<<<P.NAGG, 256, 0, stream>>>(P);
}

// Round 12
// 170.208 us; speedup vs baseline: 1.0551x; 1.0551x over previous
//
#include <hip/hip_runtime.h>

// GCN encoder: 2x (dense transform -> symmetric-normalized neighbor aggregation)
// R3: bf16x3 split MFMA GEMMs (no fp32 MFMA on CDNA4), W pre-swizzled.
// R4: aggregation gather tables bf16 -> halved beyond-L2 gather traffic.
// R5 FAILED: cross-thread fence race in ticket scan -> OOB -> abort.
// R6/R7: race-free fusions + atomic-free bucketed CSR build.
// R8 FAILED / R9 REGRESSED: cooperative grid.sync costs ~100 us on MI355X
//     (device-wide flush across 8 non-coherent XCD L2s); multi-dispatch wins.
// R10: 6 dispatches, 173.8 us (best). Marginal boundary cost ~2-4 us.
// R11 REGRESSED (179.6): agg1+gemm2 LDS fusion dropped agg occupancy 69%->26%
//     (34.8 KB LDS tile + serial 16-node waves); delivered gather BW collapsed.
//     Lesson: for latency/BW-bound gathers, occupancy > traffic fusion.
// R12: exact revert to R10.

typedef __attribute__((ext_vector_type(8))) short short8;
typedef __attribute__((ext_vector_type(4))) float float4v;

constexpr int PB = 128;  // partition blocks (histogram/scatter chunks)

static __device__ __forceinline__ ushort f2bf(float f) {
  union { float f; unsigned u; } c; c.f = f;
  unsigned u = c.u;
  return (ushort)((u + 0x7fffu + ((u >> 16) & 1u)) >> 16);  // RNE
}
static __device__ __forceinline__ float bf2f(ushort h) {
  union { unsigned u; float f; } c; c.u = ((unsigned)h) << 16;
  return c.f;
}
static __device__ __forceinline__ float bfhi(unsigned packed) {
  union { unsigned u; float f; } c; c.u = packed & 0xffff0000u;
  return c.f;
}
static __device__ __forceinline__ float bflo(unsigned packed) {
  union { unsigned u; float f; } c; c.u = packed << 16;
  return c.f;
}

struct MegaParams {
  const float* x;
  const int* src;
  const int* dst;
  const float* W1;
  const float* b1;
  const float* W2;
  const float* b2;
  int N, E, NBK, EPB, GB, NAGG;
  int* cnt_mat;
  int* bases;      // [NBK+1] bucket base offsets (published by scatter kernel)
  unsigned* part;
  int* row_ptr;
  float* dinv;
  int* col;
  ushort* h;
  ushort* h1hi;
  ushort* h1lo;
  ushort* h2;
  ushort* w1hi;
  ushort* w1lo;
  ushort* w2hi;
  ushort* w2lo;
  float* out;
};

// W swizzle: one 16x32 B-fragment tile (64 lanes).
// Layout [ktile][ntile][lane][j]: B[k=(lane>>4)*8+j][n=lane&15]
static __device__ __forceinline__ void wswz_tile(const float* __restrict__ W,
                                                 ushort* __restrict__ whi,
                                                 ushort* __restrict__ wlo,
                                                 int M, int tile, int lane) {
  int ntiles = M >> 4;
  int kt = tile / ntiles, nt = tile % ntiles;
  int colg = nt * 16 + (lane & 15);
  int krow = kt * 32 + (lane >> 4) * 8;
  size_t o = ((size_t)tile * 64 + lane) * 8;
#pragma unroll
  for (int j = 0; j < 8; j++) {
    float v = W[(size_t)(krow + j) * M + colg];
    ushort h = f2bf(v);
    whi[o + j] = h;
    wlo[o + j] = f2bf(v - bf2f(h));
  }
}

// ---- K1: bucket histogram (bid<PB) + W swizzles (bid in [PB,PB+12)) ------
__global__ __launch_bounds__(256) void k_g1(MegaParams P) {
  __shared__ int hist[512];
  int bid = blockIdx.x, t = threadIdx.x;
  if (bid >= PB) {
    int tile = (bid - PB) * 4 + (t >> 6);
    int lane = t & 63;
    if (tile < 32) wswz_tile(P.W1, P.w1hi, P.w1lo, 128, tile, lane);
    else           wswz_tile(P.W2, P.w2hi, P.w2lo, 64, tile - 32, lane);
    return;
  }
  for (int k = t; k < P.NBK; k += 256) hist[k] = 0;
  __syncthreads();
  int start = bid * P.EPB;
  int stop = min(P.E, start + P.EPB);
  for (int e = start + t * 4; e < stop; e += 1024) {
    if (e + 4 <= stop) {
      int4 d = *(const int4*)(P.dst + e);
      atomicAdd(&hist[d.x >> 7], 1);
      atomicAdd(&hist[d.y >> 7], 1);
      atomicAdd(&hist[d.z >> 7], 1);
      atomicAdd(&hist[d.w >> 7], 1);
    } else {
      for (int j = e; j < stop; j++) atomicAdd(&hist[P.dst[j] >> 7], 1);
    }
  }
  __syncthreads();
  for (int k = t; k < P.NBK; k += 256) P.cnt_mat[k * PB + bid] = hist[k];
}

// ---- gemm1 block: C[64 rows, 128] = A @ W1, fp32 A split to bf16 hi/lo ----
static __device__ void gemm1_block(int gb, const MegaParams& P) {
  constexpr int K = 128, M = 128, NT = M / 16;
  int t = threadIdx.x;
  int lane = t & 63;
  int wv = t >> 6;
  int quad = lane >> 4, lo16 = lane & 15;
  int rowbase = gb * 64 + wv * 16;
  int arow = rowbase + lo16;
  bool arow_ok = arow < P.N;
  float4v acc[NT];
#pragma unroll
  for (int nt = 0; nt < NT; nt++) acc[nt] = (float4v){0.f, 0.f, 0.f, 0.f};
  for (int kt = 0; kt < 4; kt++) {
    short8 ahi, alo;
    float av[8];
    if (arow_ok) {
      const float* ap = P.x + (size_t)arow * K + kt * 32 + quad * 8;
      float4 a0 = *(const float4*)ap;
      float4 a1 = *(const float4*)(ap + 4);
      av[0] = a0.x; av[1] = a0.y; av[2] = a0.z; av[3] = a0.w;
      av[4] = a1.x; av[5] = a1.y; av[6] = a1.z; av[7] = a1.w;
    } else {
#pragma unroll
      for (int j = 0; j < 8; j++) av[j] = 0.f;
    }
#pragma unroll
    for (int j = 0; j < 8; j++) {
      ushort hh = f2bf(av[j]);
      ahi[j] = (short)hh;
      alo[j] = (short)f2bf(av[j] - bf2f(hh));
    }
    const ushort* ph = P.w1hi + ((size_t)(kt * NT) * 64 + lane) * 8;
    const ushort* pl = P.w1lo + ((size_t)(kt * NT) * 64 + lane) * 8;
#pragma unroll
    for (int nt = 0; nt < NT; nt++) {
      short8 bhi = *(const short8*)(ph + nt * 512);
      short8 blo = *(const short8*)(pl + nt * 512);
      acc[nt] = __builtin_amdgcn_mfma_f32_16x16x32_bf16(ahi, bhi, acc[nt], 0, 0, 0);
      acc[nt] = __builtin_amdgcn_mfma_f32_16x16x32_bf16(alo, bhi, acc[nt], 0, 0, 0);
      acc[nt] = __builtin_amdgcn_mfma_f32_16x16x32_bf16(ahi, blo, acc[nt], 0, 0, 0);
    }
  }
  // D layout (m89-verified): col = lane&15, row = quad*4 + reg
#pragma unroll
  for (int nt = 0; nt < NT; nt++) {
#pragma unroll
    for (int r = 0; r < 4; r++) {
      int row = rowbase + quad * 4 + r;
      if (row < P.N) P.h[(size_t)row * M + nt * 16 + lo16] = f2bf(acc[nt][r]);
    }
  }
}

// ---- K2: partition scatter w/ self-computed prefixes (bid<PB) || gemm1 ----
__global__ __launch_bounds__(256) void k_g2(MegaParams P) {
  __shared__ int buf[256];
  __shared__ int base[512];
  __shared__ int tot[512];
  __shared__ int cur[512];
  int bid = blockIdx.x, t = threadIdx.x;
  if (bid >= PB) {
    gemm1_block(bid - PB, P);
    return;
  }
  for (int k = t; k < P.NBK; k += 256) {
    const int* row = P.cnt_mat + (size_t)k * PB;
    int pre = 0, s = 0;
    for (int b = 0; b < PB; b++) {
      int c = row[b];
      s += c;
      if (b < bid) pre += c;
    }
    tot[k] = s;
    cur[k] = pre;
  }
  __syncthreads();
  {
    int carry = 0;
    for (int b0 = 0; b0 < 512; b0 += 256) {
      int idx = b0 + t;
      int v = (idx < P.NBK) ? tot[idx] : 0;
      buf[t] = v;
      __syncthreads();
      for (int off = 1; off < 256; off <<= 1) {
        int add = (t >= off) ? buf[t - off] : 0;
        __syncthreads();
        buf[t] += add;
        __syncthreads();
      }
      base[idx] = carry + buf[t] - v;
      carry += buf[255];
      __syncthreads();
    }
  }
  for (int k = t; k < P.NBK; k += 256) cur[k] += base[k];
  if (bid == 0)
    for (int k = t; k <= P.NBK; k += 256) P.bases[k] = base[k];
  __syncthreads();
  int start = bid * P.EPB, stop = min(P.E, start + P.EPB);
  for (int e = start + t * 4; e < stop; e += 1024) {
    if (e + 4 <= stop) {
      int4 s = *(const int4*)(P.src + e);
      int4 d = *(const int4*)(P.dst + e);
      int p;
      p = atomicAdd(&cur[d.x >> 7], 1); P.part[p] = (unsigned)s.x | ((unsigned)(d.x & 127) << 25);
      p = atomicAdd(&cur[d.y >> 7], 1); P.part[p] = (unsigned)s.y | ((unsigned)(d.y & 127) << 25);
      p = atomicAdd(&cur[d.z >> 7], 1); P.part[p] = (unsigned)s.z | ((unsigned)(d.z & 127) << 25);
      p = atomicAdd(&cur[d.w >> 7], 1); P.part[p] = (unsigned)s.w | ((unsigned)(d.w & 127) << 25);
    } else {
      for (int j = e; j < stop; j++) {
        int p2 = atomicAdd(&cur[P.dst[j] >> 7], 1);
        P.part[p2] = (unsigned)P.src[j] | ((unsigned)(P.dst[j] & 127) << 25);
      }
    }
  }
}

// ---- K3: per-bucket local CSR (LDS count/scan/place); bases from K2 -------
__global__ __launch_bounds__(256) void k_g3(MegaParams P) {
  __shared__ int buf[256];
  __shared__ int cnt[128];
  __shared__ int cur[128];
  int bid = blockIdx.x, t = threadIdx.x;
  int beg = P.bases[bid], end = P.bases[bid + 1];
  if (t < 128) cnt[t] = 0;
  __syncthreads();
  for (int e = beg + t; e < end; e += 256) atomicAdd(&cnt[P.part[e] >> 25], 1);
  __syncthreads();
  int v = (t < 128) ? cnt[t] : 0;
  buf[t] = v;
  __syncthreads();
#pragma unroll
  for (int off = 1; off < 256; off <<= 1) {
    int add = (t >= off) ? buf[t - off] : 0;
    __syncthreads();
    buf[t] += add;
    __syncthreads();
  }
  if (t < 128) {
    int excl = buf[t] - v;
    cur[t] = beg + excl;
    int node = bid * 128 + t;
    if (node < P.N) {
      P.row_ptr[node] = beg + excl;
      P.dinv[node] = rsqrtf((float)(v + 1));  // +1 self loop
    }
  }
  if (bid == 0 && t == 0) P.row_ptr[P.N] = P.E;
  __syncthreads();
  for (int e = beg + t; e < end; e += 256) {
    unsigned p = P.part[e];
    int pos = atomicAdd(&cur[p >> 25], 1);
    P.col[pos] = (int)(p & 0x01FFFFFFu);
  }
}

// ---- aggregation: one wave per node, channels across lanes ----
template <int C, bool RELU, bool SPLIT>
static __device__ void agg_block(int vb, const MegaParams& P,
                                 const ushort* __restrict__ Hb,
                                 const float* __restrict__ bias,
                                 float* __restrict__ out,
                                 ushort* __restrict__ outhi,
                                 ushort* __restrict__ outlo) {
  constexpr int VPL = C / 64;  // 2 (C=128) or 1 (C=64)
  int lane = threadIdx.x & 63;
  int v = vb * 4 + (threadIdx.x >> 6);
  if (v >= P.N) return;
  float dv = P.dinv[v];
  float acc0 = 0.f, acc1 = 0.f;
  auto loadp = [&](int s) -> unsigned {
    if (VPL == 2) return *(const unsigned*)(Hb + (size_t)s * C + lane * 2);
    else          return (unsigned)Hb[(size_t)s * C + lane];
  };
  {
    unsigned u = loadp(v);  // self loop (weight dv)
    if (VPL == 2) { acc0 = dv * bflo(u); acc1 = dv * bfhi(u); }
    else          { acc0 = dv * bf2f((ushort)u); }
  }
  int beg = P.row_ptr[v], end = P.row_ptr[v + 1];
  for (int base = beg; base < end; base += 64) {
    int m = end - base;
    if (m > 64) m = 64;
    int sl = 0;
    float wl = 0.f;
    if (lane < m) {
      sl = P.col[base + lane];
      wl = P.dinv[sl];
    }
    int j = 0;
    for (; j + 8 <= m; j += 8) {
      int s[8]; float wq[8]; unsigned u[8];
#pragma unroll
      for (int q = 0; q < 8; q++) { s[q] = __shfl(sl, j + q); wq[q] = __shfl(wl, j + q); }
#pragma unroll
      for (int q = 0; q < 8; q++) u[q] = loadp(s[q]);
#pragma unroll
      for (int q = 0; q < 8; q++) {
        if (VPL == 2) {
          acc0 = fmaf(wq[q], bflo(u[q]), acc0);
          acc1 = fmaf(wq[q], bfhi(u[q]), acc1);
        } else {
          acc0 = fmaf(wq[q], bf2f((ushort)u[q]), acc0);
        }
      }
    }
    for (; j + 4 <= m; j += 4) {
      int s[4]; float wq[4]; unsigned u[4];
#pragma unroll
      for (int q = 0; q < 4; q++) { s[q] = __shfl(sl, j + q); wq[q] = __shfl(wl, j + q); }
#pragma unroll
      for (int q = 0; q < 4; q++) u[q] = loadp(s[q]);
#pragma unroll
      for (int q = 0; q < 4; q++) {
        if (VPL == 2) {
          acc0 = fmaf(wq[q], bflo(u[q]), acc0);
          acc1 = fmaf(wq[q], bfhi(u[q]), acc1);
        } else {
          acc0 = fmaf(wq[q], bf2f((ushort)u[q]), acc0);
        }
      }
    }
    for (; j < m; j++) {
      int s = __shfl(sl, j);
      float wv = __shfl(wl, j);
      unsigned u = loadp(s);
      if (VPL == 2) {
        acc0 = fmaf(wv, bflo(u), acc0);
        acc1 = fmaf(wv, bfhi(u), acc1);
      } else {
        acc0 = fmaf(wv, bf2f((ushort)u), acc0);
      }
    }
  }
  float r0 = fmaf(dv, acc0, bias[lane * VPL + 0]);
  if (RELU) r0 = fmaxf(r0, 0.f);
  if (VPL == 2) {
    float r1 = fmaf(dv, acc1, bias[lane * VPL + 1]);
    if (RELU) r1 = fmaxf(r1, 0.f);
    if (SPLIT) {
      ushort h0 = f2bf(r0), h1 = f2bf(r1);
      ushort l0 = f2bf(r0 - bf2f(h0)), l1 = f2bf(r1 - bf2f(h1));
      ((unsigned*)outhi)[(size_t)v * (C / 2) + lane] = (unsigned)h0 | ((unsigned)h1 << 16);
      ((unsigned*)outlo)[(size_t)v * (C / 2) + lane] = (unsigned)l0 | ((unsigned)l1 << 16);
    } else {
      *(float2*)&out[(size_t)v * C + lane * 2] = make_float2(r0, r1);
    }
  } else {
    out[(size_t)v * C + lane] = r0;
  }
}

// ---- K5: gemm2 block: PRESPLIT bf16 hi/lo in, bf16 out, M=64 ----
__global__ __launch_bounds__(256) void k_g5(MegaParams P) {
  constexpr int K = 128, M = 64, NT = M / 16;
  int t = threadIdx.x;
  int lane = t & 63;
  int wv = t >> 6;
  int quad = lane >> 4, lo16 = lane & 15;
  int rowbase = blockIdx.x * 64 + wv * 16;
  int arow = rowbase + lo16;
  bool arow_ok = arow < P.N;
  float4v acc[NT];
#pragma unroll
  for (int nt = 0; nt < NT; nt++) acc[nt] = (float4v){0.f, 0.f, 0.f, 0.f};
  for (int kt = 0; kt < 4; kt++) {
    short8 ahi, alo;
    if (arow_ok) {
      size_t ao = (size_t)arow * K + kt * 32 + quad * 8;
      ahi = *(const short8*)(P.h1hi + ao);
      alo = *(const short8*)(P.h1lo + ao);
    } else {
      ahi = (short8)0; alo = (short8)0;
    }
    const ushort* ph = P.w2hi + ((size_t)(kt * NT) * 64 + lane) * 8;
    const ushort* pl = P.w2lo + ((size_t)(kt * NT) * 64 + lane) * 8;
#pragma unroll
    for (int nt = 0; nt < NT; nt++) {
      short8 bhi = *(const short8*)(ph + nt * 512);
      short8 blo = *(const short8*)(pl + nt * 512);
      acc[nt] = __builtin_amdgcn_mfma_f32_16x16x32_bf16(ahi, bhi, acc[nt], 0, 0, 0);
      acc[nt] = __builtin_amdgcn_mfma_f32_16x16x32_bf16(alo, bhi, acc[nt], 0, 0, 0);
      acc[nt] = __builtin_amdgcn_mfma_f32_16x16x32_bf16(ahi, blo, acc[nt], 0, 0, 0);
    }
  }
#pragma unroll
  for (int nt = 0; nt < NT; nt++) {
#pragma unroll
    for (int r = 0; r < 4; r++) {
      int row = rowbase + quad * 4 + r;
      if (row < P.N) P.h2[(size_t)row * M + nt * 16 + lo16] = f2bf(acc[nt][r]);
    }
  }
}

__global__ __launch_bounds__(256) void k_g4(MegaParams P) {
  agg_block<128, true, true>(blockIdx.x, P, P.h, P.b1, nullptr, P.h1hi, P.h1lo);
}
__global__ __launch_bounds__(256) void k_g6(MegaParams P) {
  agg_block<64, false, false>(blockIdx.x, P, P.h2, P.b2, P.out, nullptr, nullptr);
}

extern "C" void kernel_launch(void* const* d_in, const int* in_sizes, int n_in,
                              void* d_out, int out_size, void* d_ws, size_t ws_size,
                              hipStream_t stream) {
  MegaParams P;
  P.x  = (const float*)d_in[0];
  const int* ei = (const int*)d_in[1];
  P.W1 = (const float*)d_in[2];
  P.b1 = (const float*)d_in[3];
  P.W2 = (const float*)d_in[4];
  P.b2 = (const float*)d_in[5];
  P.N = in_sizes[0] / 128;
  P.E = in_sizes[1] / 2;
  P.src = ei;
  P.dst = ei + P.E;
  P.NBK = (P.N + 127) / 128;                   // 391; must be <= 511
  P.EPB = ((P.E + PB - 1) / PB + 3) & ~3;      // edges per partition block, x4
  P.GB = (P.N + 63) / 64;                      // 782
  P.NAGG = (P.N + 3) / 4;                      // 12500

  auto al = [](size_t v) { return (v + 255) & ~(size_t)255; };
  char* w = (char*)d_ws;
  P.cnt_mat = (int*)w;      w += al((size_t)P.NBK * PB * 4);
  P.bases   = (int*)w;      w += al((size_t)(P.NBK + 1) * 4);
  P.part    = (unsigned*)w; w += al((size_t)P.E * 4);
  P.row_ptr = (int*)w;      w += al((size_t)(P.N + 1) * 4);
  P.dinv    = (float*)w;    w += al((size_t)P.N * 4);
  P.col     = (int*)w;      w += al((size_t)P.E * 4);
  P.h       = (ushort*)w;   w += al((size_t)P.N * 128 * 2);
  P.h1hi    = (ushort*)w;   w += al((size_t)P.N * 128 * 2);
  P.h1lo    = (ushort*)w;   w += al((size_t)P.N * 128 * 2);
  P.h2      = (ushort*)w;   w += al((size_t)P.N * 64 * 2);
  P.w1hi    = (ushort*)w;   w += al((size_t)128 * 128 * 2);
  P.w1lo    = (ushort*)w;   w += al((size_t)128 * 128 * 2);
  P.w2hi    = (ushort*)w;   w += al((size_t)128 * 64 * 2);
  P.w2lo    = (ushort*)w;   w += al((size_t)128 * 64 * 2);
  P.out = (float*)d_out;

  k_g1<<<PB + 12, 256, 0, stream>>>(P);
  k_g2<<<PB + P.GB, 256, 0, stream>>>(P);
  k_g3<<<P.NBK, 256, 0, stream>>>(P);
  k_g4<<<P.NAGG, 256, 0, stream>>>(P);
  k_g5<<<P.GB, 256, 0, stream>>>(P);
  k_g6<<<P.NAGG, 256, 0, stream>>>(P);
}

// Round 13
// 168.323 us; speedup vs baseline: 1.0670x; 1.0112x over previous
//
#include <hip/hip_runtime.h>

// GCN encoder: 2x (dense transform -> symmetric-normalized neighbor aggregation)
// R3: bf16x3 split MFMA GEMMs (no fp32 MFMA on CDNA4), W pre-swizzled.
// R4: aggregation gather tables bf16 -> halved beyond-L2 gather traffic.
// R5 FAILED: cross-thread fence race in ticket scan -> OOB -> abort.
// R6/R7: race-free fusions + atomic-free bucketed CSR build.
// R8 FAILED / R9 REGRESSED: cooperative grid.sync ~77-100 us each on MI355X
//     (8 non-coherent XCD L2s); multi-dispatch wins.
// R10/R12: 6 dispatches (dependency minimum), 170.2 us best.
// R11 REGRESSED: agg+gemm LDS fusion killed occupancy; occupancy > fusion.
// R13: persistent grid-stride for the three barrier-free big-grid kernels
//     (agg1 12500->2048, agg2 12500->2048, gemm2 782->1024 blocks). Theory:
//     ~10 us/dispatch residual is block-issue ramp+drain, not launch latency;
//     6x fewer block issues on the big grids should recover part of it.

typedef __attribute__((ext_vector_type(8))) short short8;
typedef __attribute__((ext_vector_type(4))) float float4v;

constexpr int PB = 128;  // partition blocks (histogram/scatter chunks)
constexpr int PERS = 2048;  // persistent grid for agg kernels (8 blocks/CU)

static __device__ __forceinline__ ushort f2bf(float f) {
  union { float f; unsigned u; } c; c.f = f;
  unsigned u = c.u;
  return (ushort)((u + 0x7fffu + ((u >> 16) & 1u)) >> 16);  // RNE
}
static __device__ __forceinline__ float bf2f(ushort h) {
  union { unsigned u; float f; } c; c.u = ((unsigned)h) << 16;
  return c.f;
}
static __device__ __forceinline__ float bfhi(unsigned packed) {
  union { unsigned u; float f; } c; c.u = packed & 0xffff0000u;
  return c.f;
}
static __device__ __forceinline__ float bflo(unsigned packed) {
  union { unsigned u; float f; } c; c.u = packed << 16;
  return c.f;
}

struct MegaParams {
  const float* x;
  const int* src;
  const int* dst;
  const float* W1;
  const float* b1;
  const float* W2;
  const float* b2;
  int N, E, NBK, EPB, GB, NAGG;
  int* cnt_mat;
  int* bases;      // [NBK+1] bucket base offsets (published by scatter kernel)
  unsigned* part;
  int* row_ptr;
  float* dinv;
  int* col;
  ushort* h;
  ushort* h1hi;
  ushort* h1lo;
  ushort* h2;
  ushort* w1hi;
  ushort* w1lo;
  ushort* w2hi;
  ushort* w2lo;
  float* out;
};

// W swizzle: one 16x32 B-fragment tile (64 lanes).
// Layout [ktile][ntile][lane][j]: B[k=(lane>>4)*8+j][n=lane&15]
static __device__ __forceinline__ void wswz_tile(const float* __restrict__ W,
                                                 ushort* __restrict__ whi,
                                                 ushort* __restrict__ wlo,
                                                 int M, int tile, int lane) {
  int ntiles = M >> 4;
  int kt = tile / ntiles, nt = tile % ntiles;
  int colg = nt * 16 + (lane & 15);
  int krow = kt * 32 + (lane >> 4) * 8;
  size_t o = ((size_t)tile * 64 + lane) * 8;
#pragma unroll
  for (int j = 0; j < 8; j++) {
    float v = W[(size_t)(krow + j) * M + colg];
    ushort h = f2bf(v);
    whi[o + j] = h;
    wlo[o + j] = f2bf(v - bf2f(h));
  }
}

// ---- K1: bucket histogram (bid<PB) + W swizzles (bid in [PB,PB+12)) ------
__global__ __launch_bounds__(256) void k_g1(MegaParams P) {
  __shared__ int hist[512];
  int bid = blockIdx.x, t = threadIdx.x;
  if (bid >= PB) {
    int tile = (bid - PB) * 4 + (t >> 6);
    int lane = t & 63;
    if (tile < 32) wswz_tile(P.W1, P.w1hi, P.w1lo, 128, tile, lane);
    else           wswz_tile(P.W2, P.w2hi, P.w2lo, 64, tile - 32, lane);
    return;
  }
  for (int k = t; k < P.NBK; k += 256) hist[k] = 0;
  __syncthreads();
  int start = bid * P.EPB;
  int stop = min(P.E, start + P.EPB);
  for (int e = start + t * 4; e < stop; e += 1024) {
    if (e + 4 <= stop) {
      int4 d = *(const int4*)(P.dst + e);
      atomicAdd(&hist[d.x >> 7], 1);
      atomicAdd(&hist[d.y >> 7], 1);
      atomicAdd(&hist[d.z >> 7], 1);
      atomicAdd(&hist[d.w >> 7], 1);
    } else {
      for (int j = e; j < stop; j++) atomicAdd(&hist[P.dst[j] >> 7], 1);
    }
  }
  __syncthreads();
  for (int k = t; k < P.NBK; k += 256) P.cnt_mat[k * PB + bid] = hist[k];
}

// ---- gemm1 block: C[64 rows, 128] = A @ W1, fp32 A split to bf16 hi/lo ----
static __device__ void gemm1_block(int gb, const MegaParams& P) {
  constexpr int K = 128, M = 128, NT = M / 16;
  int t = threadIdx.x;
  int lane = t & 63;
  int wv = t >> 6;
  int quad = lane >> 4, lo16 = lane & 15;
  int rowbase = gb * 64 + wv * 16;
  int arow = rowbase + lo16;
  bool arow_ok = arow < P.N;
  float4v acc[NT];
#pragma unroll
  for (int nt = 0; nt < NT; nt++) acc[nt] = (float4v){0.f, 0.f, 0.f, 0.f};
  for (int kt = 0; kt < 4; kt++) {
    short8 ahi, alo;
    float av[8];
    if (arow_ok) {
      const float* ap = P.x + (size_t)arow * K + kt * 32 + quad * 8;
      float4 a0 = *(const float4*)ap;
      float4 a1 = *(const float4*)(ap + 4);
      av[0] = a0.x; av[1] = a0.y; av[2] = a0.z; av[3] = a0.w;
      av[4] = a1.x; av[5] = a1.y; av[6] = a1.z; av[7] = a1.w;
    } else {
#pragma unroll
      for (int j = 0; j < 8; j++) av[j] = 0.f;
    }
#pragma unroll
    for (int j = 0; j < 8; j++) {
      ushort hh = f2bf(av[j]);
      ahi[j] = (short)hh;
      alo[j] = (short)f2bf(av[j] - bf2f(hh));
    }
    const ushort* ph = P.w1hi + ((size_t)(kt * NT) * 64 + lane) * 8;
    const ushort* pl = P.w1lo + ((size_t)(kt * NT) * 64 + lane) * 8;
#pragma unroll
    for (int nt = 0; nt < NT; nt++) {
      short8 bhi = *(const short8*)(ph + nt * 512);
      short8 blo = *(const short8*)(pl + nt * 512);
      acc[nt] = __builtin_amdgcn_mfma_f32_16x16x32_bf16(ahi, bhi, acc[nt], 0, 0, 0);
      acc[nt] = __builtin_amdgcn_mfma_f32_16x16x32_bf16(alo, bhi, acc[nt], 0, 0, 0);
      acc[nt] = __builtin_amdgcn_mfma_f32_16x16x32_bf16(ahi, blo, acc[nt], 0, 0, 0);
    }
  }
  // D layout (m89-verified): col = lane&15, row = quad*4 + reg
#pragma unroll
  for (int nt = 0; nt < NT; nt++) {
#pragma unroll
    for (int r = 0; r < 4; r++) {
      int row = rowbase + quad * 4 + r;
      if (row < P.N) P.h[(size_t)row * M + nt * 16 + lo16] = f2bf(acc[nt][r]);
    }
  }
}

// ---- K2: partition scatter w/ self-computed prefixes (bid<PB) || gemm1 ----
__global__ __launch_bounds__(256) void k_g2(MegaParams P) {
  __shared__ int buf[256];
  __shared__ int base[512];
  __shared__ int tot[512];
  __shared__ int cur[512];
  int bid = blockIdx.x, t = threadIdx.x;
  if (bid >= PB) {
    gemm1_block(bid - PB, P);
    return;
  }
  for (int k = t; k < P.NBK; k += 256) {
    const int* row = P.cnt_mat + (size_t)k * PB;
    int pre = 0, s = 0;
    for (int b = 0; b < PB; b++) {
      int c = row[b];
      s += c;
      if (b < bid) pre += c;
    }
    tot[k] = s;
    cur[k] = pre;
  }
  __syncthreads();
  {
    int carry = 0;
    for (int b0 = 0; b0 < 512; b0 += 256) {
      int idx = b0 + t;
      int v = (idx < P.NBK) ? tot[idx] : 0;
      buf[t] = v;
      __syncthreads();
      for (int off = 1; off < 256; off <<= 1) {
        int add = (t >= off) ? buf[t - off] : 0;
        __syncthreads();
        buf[t] += add;
        __syncthreads();
      }
      base[idx] = carry + buf[t] - v;
      carry += buf[255];
      __syncthreads();
    }
  }
  for (int k = t; k < P.NBK; k += 256) cur[k] += base[k];
  if (bid == 0)
    for (int k = t; k <= P.NBK; k += 256) P.bases[k] = base[k];
  __syncthreads();
  int start = bid * P.EPB, stop = min(P.E, start + P.EPB);
  for (int e = start + t * 4; e < stop; e += 1024) {
    if (e + 4 <= stop) {
      int4 s = *(const int4*)(P.src + e);
      int4 d = *(const int4*)(P.dst + e);
      int p;
      p = atomicAdd(&cur[d.x >> 7], 1); P.part[p] = (unsigned)s.x | ((unsigned)(d.x & 127) << 25);
      p = atomicAdd(&cur[d.y >> 7], 1); P.part[p] = (unsigned)s.y | ((unsigned)(d.y & 127) << 25);
      p = atomicAdd(&cur[d.z >> 7], 1); P.part[p] = (unsigned)s.z | ((unsigned)(d.z & 127) << 25);
      p = atomicAdd(&cur[d.w >> 7], 1); P.part[p] = (unsigned)s.w | ((unsigned)(d.w & 127) << 25);
    } else {
      for (int j = e; j < stop; j++) {
        int p2 = atomicAdd(&cur[P.dst[j] >> 7], 1);
        P.part[p2] = (unsigned)P.src[j] | ((unsigned)(P.dst[j] & 127) << 25);
      }
    }
  }
}

// ---- K3: per-bucket local CSR (LDS count/scan/place); bases from K2 -------
__global__ __launch_bounds__(256) void k_g3(MegaParams P) {
  __shared__ int buf[256];
  __shared__ int cnt[128];
  __shared__ int cur[128];
  int bid = blockIdx.x, t = threadIdx.x;
  int beg = P.bases[bid], end = P.bases[bid + 1];
  if (t < 128) cnt[t] = 0;
  __syncthreads();
  for (int e = beg + t; e < end; e += 256) atomicAdd(&cnt[P.part[e] >> 25], 1);
  __syncthreads();
  int v = (t < 128) ? cnt[t] : 0;
  buf[t] = v;
  __syncthreads();
#pragma unroll
  for (int off = 1; off < 256; off <<= 1) {
    int add = (t >= off) ? buf[t - off] : 0;
    __syncthreads();
    buf[t] += add;
    __syncthreads();
  }
  if (t < 128) {
    int excl = buf[t] - v;
    cur[t] = beg + excl;
    int node = bid * 128 + t;
    if (node < P.N) {
      P.row_ptr[node] = beg + excl;
      P.dinv[node] = rsqrtf((float)(v + 1));  // +1 self loop
    }
  }
  if (bid == 0 && t == 0) P.row_ptr[P.N] = P.E;
  __syncthreads();
  for (int e = beg + t; e < end; e += 256) {
    unsigned p = P.part[e];
    int pos = atomicAdd(&cur[p >> 25], 1);
    P.col[pos] = (int)(p & 0x01FFFFFFu);
  }
}

// ---- aggregation: one wave per node, channels across lanes ----
template <int C, bool RELU, bool SPLIT>
static __device__ void agg_block(int vb, const MegaParams& P,
                                 const ushort* __restrict__ Hb,
                                 const float* __restrict__ bias,
                                 float* __restrict__ out,
                                 ushort* __restrict__ outhi,
                                 ushort* __restrict__ outlo) {
  constexpr int VPL = C / 64;  // 2 (C=128) or 1 (C=64)
  int lane = threadIdx.x & 63;
  int v = vb * 4 + (threadIdx.x >> 6);
  if (v >= P.N) return;
  float dv = P.dinv[v];
  float acc0 = 0.f, acc1 = 0.f;
  auto loadp = [&](int s) -> unsigned {
    if (VPL == 2) return *(const unsigned*)(Hb + (size_t)s * C + lane * 2);
    else          return (unsigned)Hb[(size_t)s * C + lane];
  };
  {
    unsigned u = loadp(v);  // self loop (weight dv)
    if (VPL == 2) { acc0 = dv * bflo(u); acc1 = dv * bfhi(u); }
    else          { acc0 = dv * bf2f((ushort)u); }
  }
  int beg = P.row_ptr[v], end = P.row_ptr[v + 1];
  for (int base = beg; base < end; base += 64) {
    int m = end - base;
    if (m > 64) m = 64;
    int sl = 0;
    float wl = 0.f;
    if (lane < m) {
      sl = P.col[base + lane];
      wl = P.dinv[sl];
    }
    int j = 0;
    for (; j + 8 <= m; j += 8) {
      int s[8]; float wq[8]; unsigned u[8];
#pragma unroll
      for (int q = 0; q < 8; q++) { s[q] = __shfl(sl, j + q); wq[q] = __shfl(wl, j + q); }
#pragma unroll
      for (int q = 0; q < 8; q++) u[q] = loadp(s[q]);
#pragma unroll
      for (int q = 0; q < 8; q++) {
        if (VPL == 2) {
          acc0 = fmaf(wq[q], bflo(u[q]), acc0);
          acc1 = fmaf(wq[q], bfhi(u[q]), acc1);
        } else {
          acc0 = fmaf(wq[q], bf2f((ushort)u[q]), acc0);
        }
      }
    }
    for (; j + 4 <= m; j += 4) {
      int s[4]; float wq[4]; unsigned u[4];
#pragma unroll
      for (int q = 0; q < 4; q++) { s[q] = __shfl(sl, j + q); wq[q] = __shfl(wl, j + q); }
#pragma unroll
      for (int q = 0; q < 4; q++) u[q] = loadp(s[q]);
#pragma unroll
      for (int q = 0; q < 4; q++) {
        if (VPL == 2) {
          acc0 = fmaf(wq[q], bflo(u[q]), acc0);
          acc1 = fmaf(wq[q], bfhi(u[q]), acc1);
        } else {
          acc0 = fmaf(wq[q], bf2f((ushort)u[q]), acc0);
        }
      }
    }
    for (; j < m; j++) {
      int s = __shfl(sl, j);
      float wv = __shfl(wl, j);
      unsigned u = loadp(s);
      if (VPL == 2) {
        acc0 = fmaf(wv, bflo(u), acc0);
        acc1 = fmaf(wv, bfhi(u), acc1);
      } else {
        acc0 = fmaf(wv, bf2f((ushort)u), acc0);
      }
    }
  }
  float r0 = fmaf(dv, acc0, bias[lane * VPL + 0]);
  if (RELU) r0 = fmaxf(r0, 0.f);
  if (VPL == 2) {
    float r1 = fmaf(dv, acc1, bias[lane * VPL + 1]);
    if (RELU) r1 = fmaxf(r1, 0.f);
    if (SPLIT) {
      ushort h0 = f2bf(r0), h1 = f2bf(r1);
      ushort l0 = f2bf(r0 - bf2f(h0)), l1 = f2bf(r1 - bf2f(h1));
      ((unsigned*)outhi)[(size_t)v * (C / 2) + lane] = (unsigned)h0 | ((unsigned)h1 << 16);
      ((unsigned*)outlo)[(size_t)v * (C / 2) + lane] = (unsigned)l0 | ((unsigned)l1 << 16);
    } else {
      *(float2*)&out[(size_t)v * C + lane * 2] = make_float2(r0, r1);
    }
  } else {
    out[(size_t)v * C + lane] = r0;
  }
}

// ---- gemm2 body: PRESPLIT bf16 hi/lo in, bf16 out, M=64 ----
static __device__ void gemm2_block(int gb, const MegaParams& P) {
  constexpr int K = 128, M = 64, NT = M / 16;
  int t = threadIdx.x;
  int lane = t & 63;
  int wv = t >> 6;
  int quad = lane >> 4, lo16 = lane & 15;
  int rowbase = gb * 64 + wv * 16;
  int arow = rowbase + lo16;
  bool arow_ok = arow < P.N;
  float4v acc[NT];
#pragma unroll
  for (int nt = 0; nt < NT; nt++) acc[nt] = (float4v){0.f, 0.f, 0.f, 0.f};
  for (int kt = 0; kt < 4; kt++) {
    short8 ahi, alo;
    if (arow_ok) {
      size_t ao = (size_t)arow * K + kt * 32 + quad * 8;
      ahi = *(const short8*)(P.h1hi + ao);
      alo = *(const short8*)(P.h1lo + ao);
    } else {
      ahi = (short8)0; alo = (short8)0;
    }
    const ushort* ph = P.w2hi + ((size_t)(kt * NT) * 64 + lane) * 8;
    const ushort* pl = P.w2lo + ((size_t)(kt * NT) * 64 + lane) * 8;
#pragma unroll
    for (int nt = 0; nt < NT; nt++) {
      short8 bhi = *(const short8*)(ph + nt * 512);
      short8 blo = *(const short8*)(pl + nt * 512);
      acc[nt] = __builtin_amdgcn_mfma_f32_16x16x32_bf16(ahi, bhi, acc[nt], 0, 0, 0);
      acc[nt] = __builtin_amdgcn_mfma_f32_16x16x32_bf16(alo, bhi, acc[nt], 0, 0, 0);
      acc[nt] = __builtin_amdgcn_mfma_f32_16x16x32_bf16(ahi, blo, acc[nt], 0, 0, 0);
    }
  }
#pragma unroll
  for (int nt = 0; nt < NT; nt++) {
#pragma unroll
    for (int r = 0; r < 4; r++) {
      int row = rowbase + quad * 4 + r;
      if (row < P.N) P.h2[(size_t)row * M + nt * 16 + lo16] = f2bf(acc[nt][r]);
    }
  }
}

// ---- persistent grid-stride wrappers (no barriers inside bodies) ---------
__global__ __launch_bounds__(256) void k_g4(MegaParams P) {
  for (int vb = blockIdx.x; vb < P.NAGG; vb += gridDim.x)
    agg_block<128, true, true>(vb, P, P.h, P.b1, nullptr, P.h1hi, P.h1lo);
}
__global__ __launch_bounds__(256) void k_g5(MegaParams P) {
  for (int gb = blockIdx.x; gb < P.GB; gb += gridDim.x) gemm2_block(gb, P);
}
__global__ __launch_bounds__(256) void k_g6(MegaParams P) {
  for (int vb = blockIdx.x; vb < P.NAGG; vb += gridDim.x)
    agg_block<64, false, false>(vb, P, P.h2, P.b2, P.out, nullptr, nullptr);
}

extern "C" void kernel_launch(void* const* d_in, const int* in_sizes, int n_in,
                              void* d_out, int out_size, void* d_ws, size_t ws_size,
                              hipStream_t stream) {
  MegaParams P;
  P.x  = (const float*)d_in[0];
  const int* ei = (const int*)d_in[1];
  P.W1 = (const float*)d_in[2];
  P.b1 = (const float*)d_in[3];
  P.W2 = (const float*)d_in[4];
  P.b2 = (const float*)d_in[5];
  P.N = in_sizes[0] / 128;
  P.E = in_sizes[1] / 2;
  P.src = ei;
  P.dst = ei + P.E;
  P.NBK = (P.N + 127) / 128;                   // 391; must be <= 511
  P.EPB = ((P.E + PB - 1) / PB + 3) & ~3;      // edges per partition block, x4
  P.GB = (P.N + 63) / 64;                      // 782
  P.NAGG = (P.N + 3) / 4;                      // 12500

  auto al = [](size_t v) { return (v + 255) & ~(size_t)255; };
  char* w = (char*)d_ws;
  P.cnt_mat = (int*)w;      w += al((size_t)P.NBK * PB * 4);
  P.bases   = (int*)w;      w += al((size_t)(P.NBK + 1) * 4);
  P.part    = (unsigned*)w; w += al((size_t)P.E * 4);
  P.row_ptr = (int*)w;      w += al((size_t)(P.N + 1) * 4);
  P.dinv    = (float*)w;    w += al((size_t)P.N * 4);
  P.col     = (int*)w;      w += al((size_t)P.E * 4);
  P.h       = (ushort*)w;   w += al((size_t)P.N * 128 * 2);
  P.h1hi    = (ushort*)w;   w += al((size_t)P.N * 128 * 2);
  P.h1lo    = (ushort*)w;   w += al((size_t)P.N * 128 * 2);
  P.h2      = (ushort*)w;   w += al((size_t)P.N * 64 * 2);
  P.w1hi    = (ushort*)w;   w += al((size_t)128 * 128 * 2);
  P.w1lo    = (ushort*)w;   w += al((size_t)128 * 128 * 2);
  P.w2hi    = (ushort*)w;   w += al((size_t)128 * 64 * 2);
  P.w2lo    = (ushort*)w;   w += al((size_t)128 * 64 * 2);
  P.out = (float*)d_out;

  k_g1<<<PB + 12, 256, 0, stream>>>(P);
  k_g2<<<PB + P.GB, 256, 0, stream>>>(P);
  k_g3<<<P.NBK, 256, 0, stream>>>(P);
  k_g4<<<PERS, 256, 0, stream>>>(P);
  k_g5<<<1024, 256, 0, stream>>>(P);
  k_g6<<<PERS, 256, 0, stream>>>(P);
}